// Round 1
// baseline (183.384 us; speedup 1.0000x reference)
//
#include <hip/hip_runtime.h>

#define BDIM 8192
#define DDIM 256

typedef __bf16 bf16x8 __attribute__((ext_vector_type(8)));
typedef float f32x4 __attribute__((ext_vector_type(4)));
typedef unsigned short u16x4 __attribute__((ext_vector_type(4)));

__device__ inline unsigned short f2bf(float f) {
  unsigned u = __float_as_uint(f);
  u += 0x7FFFu + ((u >> 16) & 1u);  // round-to-nearest-even
  return (unsigned short)(u >> 16);
}
__device__ inline float bf2f(unsigned short h) {
  return __uint_as_float(((unsigned)h) << 16);
}

// Direct global->LDS DMA, 16B per lane. LDS dest is wave-uniform base +
// lane*16 (linear); global source is per-lane (carries the swizzle).
__device__ inline void gload_lds16(const void* g, void* l) {
  __builtin_amdgcn_global_load_lds(
      (const __attribute__((address_space(1))) void*)g,
      (__attribute__((address_space(3))) void*)l, 16, 0, 0);
}

// ---------------------------------------------------------------------------
// Kernel 1: normalize rows and convert to bf16, ONCE (amortized over the 64
// tile-reuses that previously re-converted fp32->bf16 per block).
// Rows [0,B) = text -> tn, rows [B,2B) = image -> vn. One wave per row.
// ---------------------------------------------------------------------------
__global__ __launch_bounds__(256) void norm_convert_kernel(
    const float* __restrict__ t, const float* __restrict__ v,
    unsigned short* __restrict__ tn, unsigned short* __restrict__ vn) {
  int wid = threadIdx.x >> 6, lane = threadIdx.x & 63;
  int row = blockIdx.x * 4 + wid;
  const float* src;
  unsigned short* dst;
  if (row < BDIM) {
    src = t + (size_t)row * DDIM;
    dst = tn + (size_t)row * DDIM;
  } else {
    int r = row - BDIM;
    src = v + (size_t)r * DDIM;
    dst = vn + (size_t)r * DDIM;
  }
  float4 x = reinterpret_cast<const float4*>(src)[lane];
  float ss = x.x * x.x + x.y * x.y + x.z * x.z + x.w * x.w;
  #pragma unroll
  for (int off = 1; off < 64; off <<= 1) ss += __shfl_xor(ss, off, 64);
  float sc = 1.0f / fmaxf(sqrtf(ss), 1e-12f);
  u16x4 w;
  w[0] = f2bf(x.x * sc); w[1] = f2bf(x.y * sc);
  w[2] = f2bf(x.z * sc); w[3] = f2bf(x.w * sc);
  reinterpret_cast<u16x4*>(dst)[lane] = w;
}

// ---------------------------------------------------------------------------
// Kernel 2: 128x128-tile bf16 GEMM over sim = Tn @ Vn^T with position-blind
// epilogue: every element contributes 0.7*max(s,0)^2. Diagonal and semi
// entries are fixed up by corr_kernel (sparse: <=4 per row).
//
// Staging: global_load_lds dwordx4, linear LDS [128][64] bf16 (128B rows),
// XOR swizzle byte^=((row&7)<<4) applied on the SOURCE address and on the
// ds_read address (both-sides involution). 8 rows x 8 lanes cover all 32
// banks -> conflict-free ds_read_b128.
// ---------------------------------------------------------------------------
__global__ __launch_bounds__(256) void loss_kernel(
    const unsigned short* __restrict__ tn,
    const unsigned short* __restrict__ vn, float* __restrict__ out) {
  __shared__ unsigned short As[128 * 64];  // 16 KB, swizzled content
  __shared__ unsigned short Bs[128 * 64];  // 16 KB
  __shared__ float rbuf[4];

  const int tid = threadIdx.x;
  const int lane = tid & 63;
  const int wid = tid >> 6;
  const int l15 = lane & 15;
  const int l4 = lane >> 4;
  const int rowBase = blockIdx.y * 128;
  const int colBase = blockIdx.x * 128;

  // Staging geometry: per wave, 4 rounds of 1KB per matrix.
  // LDS byte L = wid*4096 + q*1024 + lane*16
  //   row  = wid*32 + q*8 + (lane>>3)          (row&7 == lane>>3)
  //   colb = (lane&7)*16; swizzled source col = 16*((lane&7) ^ (lane>>3))
  const int srow = wid * 32 + (lane >> 3);                // + q*8 per round
  const int scol = (((lane & 7) ^ (lane >> 3)) << 4) >> 1;  // shorts
  const unsigned short* gA = tn + (size_t)(rowBase + srow) * DDIM + scol;
  const unsigned short* gB = vn + (size_t)(colBase + srow) * DDIM + scol;
  unsigned short* lA = As + wid * 2048;  // + q*512 per round (shorts)
  unsigned short* lB = Bs + wid * 2048;

  const int wr = (wid >> 1) * 64;  // wave row offset in tile
  const int wc = (wid & 1) * 64;   // wave col offset in tile

  f32x4 acc[4][4];
  #pragma unroll
  for (int i = 0; i < 4; ++i)
    #pragma unroll
    for (int j = 0; j < 4; ++j) acc[i][j] = (f32x4)(0.0f);

  for (int ks = 0; ks < 4; ++ks) {
    if (ks) __syncthreads();  // LDS consumed by previous iter's MFMAs
    #pragma unroll
    for (int q = 0; q < 4; ++q) {
      gload_lds16(gA + (size_t)q * 8 * DDIM + ks * 64, lA + q * 512);
      gload_lds16(gB + (size_t)q * 8 * DDIM + ks * 64, lB + q * 512);
    }
    __syncthreads();  // compiler drains vmcnt(0) before s_barrier
    #pragma unroll
    for (int kk = 0; kk < 2; ++kk) {
      bf16x8 af[4], bfr[4];
      const int cb = ((kk * 64 + l4 * 16) ^ ((l15 & 7) << 4)) >> 1;  // shorts
      #pragma unroll
      for (int m = 0; m < 4; ++m) {
        int row = wr + m * 16 + l15;  // row&7 == l15&7
        af[m] = *reinterpret_cast<const bf16x8*>(&As[row * 64 + cb]);
      }
      #pragma unroll
      for (int n = 0; n < 4; ++n) {
        int row = wc + n * 16 + l15;
        bfr[n] = *reinterpret_cast<const bf16x8*>(&Bs[row * 64 + cb]);
      }
      #pragma unroll
      for (int m = 0; m < 4; ++m)
        #pragma unroll
        for (int n = 0; n < 4; ++n)
          acc[m][n] = __builtin_amdgcn_mfma_f32_16x16x32_bf16(
              af[m], bfr[n], acc[m][n], 0, 0, 0);
    }
  }

  // Position-blind epilogue: 2 VALU ops per element.
  float lsum = 0.0f;
  #pragma unroll
  for (int m = 0; m < 4; ++m)
    #pragma unroll
    for (int n = 0; n < 4; ++n)
      #pragma unroll
      for (int r = 0; r < 4; ++r) {
        float u = fmaxf(acc[m][n][r], 0.0f);
        lsum = fmaf(u, u, lsum);
      }
  lsum *= 0.7f;  // LAMBDA_NEG
  #pragma unroll
  for (int off = 1; off < 64; off <<= 1) lsum += __shfl_xor(lsum, off, 64);
  if (lane == 0) rbuf[wid] = lsum;
  __syncthreads();
  if (tid == 0) atomicAdd(out, rbuf[0] + rbuf[1] + rbuf[2] + rbuf[3]);
}

// ---------------------------------------------------------------------------
// Kernel 3: sparse fixups. For each row i: diagonal (replace 0.7*max(s,0)^2
// with (s-1)^2) and up to 3 dedup'd valid semi entries (replace with
// 0.7*max(0.7-s,0)^2). Dots recomputed from the SAME bf16 arrays with fp32
// accumulation -> matches the MFMA value to ~1e-6. One wave per row.
// ---------------------------------------------------------------------------
__global__ __launch_bounds__(256) void corr_kernel(
    const unsigned short* __restrict__ tn,
    const unsigned short* __restrict__ vn, const int* __restrict__ sidx,
    float* __restrict__ out) {
  int wid = threadIdx.x >> 6, lane = threadIdx.x & 63;
  int i = blockIdx.x * 4 + wid;

  u16x4 ta = reinterpret_cast<const u16x4*>(tn + (size_t)i * DDIM)[lane];
  float t0 = bf2f(ta[0]), t1 = bf2f(ta[1]), t2 = bf2f(ta[2]), t3 = bf2f(ta[3]);

  int j0 = sidx[(size_t)i * 3 + 0];
  int j1 = sidx[(size_t)i * 3 + 1];
  int j2 = sidx[(size_t)i * 3 + 2];
  bool v0 = (j0 >= 0) & (j0 < BDIM) & (j0 != i);
  bool v1 = (j1 >= 0) & (j1 < BDIM) & (j1 != i) & !(v0 & (j1 == j0));
  bool v2 = (j2 >= 0) & (j2 < BDIM) & (j2 != i) & !(v0 & (j2 == j0)) &
            !(v1 & (j2 == j1));

  float corr = 0.0f;
  {  // diagonal
    u16x4 va = reinterpret_cast<const u16x4*>(vn + (size_t)i * DDIM)[lane];
    float d = t0 * bf2f(va[0]) + t1 * bf2f(va[1]) + t2 * bf2f(va[2]) +
              t3 * bf2f(va[3]);
    #pragma unroll
    for (int off = 1; off < 64; off <<= 1) d += __shfl_xor(d, off, 64);
    float u = fmaxf(d, 0.0f);
    corr += (d - 1.0f) * (d - 1.0f) - 0.7f * u * u;
  }
  int jj[3] = {j0, j1, j2};
  bool vv[3] = {v0, v1, v2};
  #pragma unroll
  for (int k = 0; k < 3; ++k) {
    int j = vv[k] ? jj[k] : i;  // safe address; discarded if invalid
    u16x4 va = reinterpret_cast<const u16x4*>(vn + (size_t)j * DDIM)[lane];
    float d = t0 * bf2f(va[0]) + t1 * bf2f(va[1]) + t2 * bf2f(va[2]) +
              t3 * bf2f(va[3]);
    #pragma unroll
    for (int off = 1; off < 64; off <<= 1) d += __shfl_xor(d, off, 64);
    if (vv[k]) {
      float up = fmaxf(0.7f - d, 0.0f);
      float un = fmaxf(d, 0.0f);
      corr += 0.7f * (up * up - un * un);  // GAMMA_SEMI == LAMBDA_NEG == 0.7
    }
  }
  if (lane == 0) atomicAdd(out, corr);
}

extern "C" void kernel_launch(void* const* d_in, const int* in_sizes, int n_in,
                              void* d_out, int out_size, void* d_ws,
                              size_t ws_size, hipStream_t stream) {
  const float* t = (const float*)d_in[0];
  const float* v = (const float*)d_in[1];
  const int* sidx = (const int*)d_in[2];
  float* out = (float*)d_out;
  unsigned short* tn = (unsigned short*)d_ws;             // 4 MB
  unsigned short* vn = tn + (size_t)BDIM * DDIM;          // 4 MB

  hipMemsetAsync(out, 0, sizeof(float), stream);
  norm_convert_kernel<<<4096, 256, 0, stream>>>(t, v, tn, vn);
  dim3 grid(64, 64);
  loss_kernel<<<grid, 256, 0, stream>>>(tn, vn, out);
  corr_kernel<<<2048, 256, 0, stream>>>(tn, vn, sidx, out);
}

// Round 2
// 64.191 us; speedup vs baseline: 2.8569x; 2.8569x over previous
//
#include <hip/hip_runtime.h>

#define BDIM 8192
#define DDIM 256
#define NSLOTS 512

typedef __bf16 bf16x8 __attribute__((ext_vector_type(8)));
typedef float f32x4 __attribute__((ext_vector_type(4)));
typedef unsigned short u16x4 __attribute__((ext_vector_type(4)));

__device__ inline unsigned short f2bf(float f) {
  unsigned u = __float_as_uint(f);
  u += 0x7FFFu + ((u >> 16) & 1u);  // round-to-nearest-even
  return (unsigned short)(u >> 16);
}
__device__ inline float bf2f(unsigned short h) {
  return __uint_as_float(((unsigned)h) << 16);
}

// Direct global->LDS DMA, 16B per lane. LDS dest is wave-uniform base +
// lane*16 (linear); global source is per-lane (carries the swizzle).
__device__ inline void gload_lds16(const void* g, void* l) {
  __builtin_amdgcn_global_load_lds(
      (const __attribute__((address_space(1))) void*)g,
      (__attribute__((address_space(3))) void*)l, 16, 0, 0);
}

// ---------------------------------------------------------------------------
// Kernel 1: normalize rows and convert to bf16, once. One wave per row.
// ---------------------------------------------------------------------------
__global__ __launch_bounds__(256) void norm_convert_kernel(
    const float* __restrict__ t, const float* __restrict__ v,
    unsigned short* __restrict__ tn, unsigned short* __restrict__ vn) {
  int wid = threadIdx.x >> 6, lane = threadIdx.x & 63;
  int row = blockIdx.x * 4 + wid;
  const float* src;
  unsigned short* dst;
  if (row < BDIM) {
    src = t + (size_t)row * DDIM;
    dst = tn + (size_t)row * DDIM;
  } else {
    int r = row - BDIM;
    src = v + (size_t)r * DDIM;
    dst = vn + (size_t)r * DDIM;
  }
  float4 x = reinterpret_cast<const float4*>(src)[lane];
  float ss = x.x * x.x + x.y * x.y + x.z * x.z + x.w * x.w;
  #pragma unroll
  for (int off = 1; off < 64; off <<= 1) ss += __shfl_xor(ss, off, 64);
  float sc = 1.0f / fmaxf(sqrtf(ss), 1e-12f);
  u16x4 w;
  w[0] = f2bf(x.x * sc); w[1] = f2bf(x.y * sc);
  w[2] = f2bf(x.z * sc); w[3] = f2bf(x.w * sc);
  reinterpret_cast<u16x4*>(dst)[lane] = w;
}

// ---------------------------------------------------------------------------
// Kernel 2: 128x128-tile bf16 GEMM over sim = Tn @ Vn^T, position-blind
// epilogue (every element contributes 0.7*max(s,0)^2; diagonal/semi fixed up
// sparsely by corr_kernel). Block partial -> atomicAdd into spread slots
// (NOT a single address: same-address fp32 atomics serialize at ~13ns; 8192
// of them was 107us in round 1).
// XCD-chunked block swizzle: each XCD gets 8 contiguous by-panels -> its
// private 4MB L2 holds the working set. 4096 % 8 == 0 -> simple remap is
// bijective.
// ---------------------------------------------------------------------------
__global__ __launch_bounds__(256) void loss_kernel(
    const unsigned short* __restrict__ tn,
    const unsigned short* __restrict__ vn, float* __restrict__ slots) {
  __shared__ unsigned short As[128 * 64];  // 16 KB, swizzled content
  __shared__ unsigned short Bs[128 * 64];  // 16 KB
  __shared__ float rbuf[4];

  const int tid = threadIdx.x;
  const int lane = tid & 63;
  const int wid = tid >> 6;
  const int l15 = lane & 15;
  const int l4 = lane >> 4;

  // XCD-aware bijective swizzle (nwg = 4096, 8 XCDs, 512 blocks/XCD).
  const int flat = blockIdx.y * 64 + blockIdx.x;
  const int nb = (flat & 7) * 512 + (flat >> 3);
  const int rowBase = (nb >> 6) * 128;  // by in [xcd*8, xcd*8+8)
  const int colBase = (nb & 63) * 128;

  // Staging geometry: per wave, 4 rounds of 1KB per matrix.
  // LDS byte L = wid*4096 + q*1024 + lane*16
  //   row  = wid*32 + q*8 + (lane>>3)          (row&7 == lane>>3)
  //   colb = (lane&7)*16; swizzled source col = 16*((lane&7) ^ (lane>>3))
  const int srow = wid * 32 + (lane >> 3);                  // + q*8 per round
  const int scol = (((lane & 7) ^ (lane >> 3)) << 4) >> 1;  // shorts
  const unsigned short* gA = tn + (size_t)(rowBase + srow) * DDIM + scol;
  const unsigned short* gB = vn + (size_t)(colBase + srow) * DDIM + scol;
  unsigned short* lA = As + wid * 2048;  // + q*512 per round (shorts)
  unsigned short* lB = Bs + wid * 2048;

  const int wr = (wid >> 1) * 64;  // wave row offset in tile
  const int wc = (wid & 1) * 64;   // wave col offset in tile

  f32x4 acc[4][4];
  #pragma unroll
  for (int i = 0; i < 4; ++i)
    #pragma unroll
    for (int j = 0; j < 4; ++j) acc[i][j] = (f32x4)(0.0f);

  for (int ks = 0; ks < 4; ++ks) {
    if (ks) __syncthreads();  // LDS consumed by previous iter's MFMAs
    #pragma unroll
    for (int q = 0; q < 4; ++q) {
      gload_lds16(gA + (size_t)q * 8 * DDIM + ks * 64, lA + q * 512);
      gload_lds16(gB + (size_t)q * 8 * DDIM + ks * 64, lB + q * 512);
    }
    __syncthreads();  // compiler drains vmcnt(0) before s_barrier
    #pragma unroll
    for (int kk = 0; kk < 2; ++kk) {
      bf16x8 af[4], bfr[4];
      const int cb = ((kk * 64 + l4 * 16) ^ ((l15 & 7) << 4)) >> 1;  // shorts
      #pragma unroll
      for (int m = 0; m < 4; ++m) {
        int row = wr + m * 16 + l15;  // row&7 == l15&7
        af[m] = *reinterpret_cast<const bf16x8*>(&As[row * 64 + cb]);
      }
      #pragma unroll
      for (int n = 0; n < 4; ++n) {
        int row = wc + n * 16 + l15;
        bfr[n] = *reinterpret_cast<const bf16x8*>(&Bs[row * 64 + cb]);
      }
      #pragma unroll
      for (int m = 0; m < 4; ++m)
        #pragma unroll
        for (int n = 0; n < 4; ++n)
          acc[m][n] = __builtin_amdgcn_mfma_f32_16x16x32_bf16(
              af[m], bfr[n], acc[m][n], 0, 0, 0);
    }
  }

  // Position-blind epilogue: 2 VALU ops per element.
  float lsum = 0.0f;
  #pragma unroll
  for (int m = 0; m < 4; ++m)
    #pragma unroll
    for (int n = 0; n < 4; ++n)
      #pragma unroll
      for (int r = 0; r < 4; ++r) {
        float u = fmaxf(acc[m][n][r], 0.0f);
        lsum = fmaf(u, u, lsum);
      }
  lsum *= 0.7f;  // LAMBDA_NEG
  #pragma unroll
  for (int off = 1; off < 64; off <<= 1) lsum += __shfl_xor(lsum, off, 64);
  if (lane == 0) rbuf[wid] = lsum;
  __syncthreads();
  if (tid == 0)
    atomicAdd(&slots[flat & (NSLOTS - 1)],
              rbuf[0] + rbuf[1] + rbuf[2] + rbuf[3]);
}

// ---------------------------------------------------------------------------
// Kernel 3: sparse fixups, one wave per row (all 8192 waves co-resident ->
// pure latency). Per-wave result -> spread slots (16-deep chains max).
// ---------------------------------------------------------------------------
__global__ __launch_bounds__(256) void corr_kernel(
    const unsigned short* __restrict__ tn,
    const unsigned short* __restrict__ vn, const int* __restrict__ sidx,
    float* __restrict__ slots) {
  int wid = threadIdx.x >> 6, lane = threadIdx.x & 63;
  int i = blockIdx.x * 4 + wid;

  u16x4 ta = reinterpret_cast<const u16x4*>(tn + (size_t)i * DDIM)[lane];
  float t0 = bf2f(ta[0]), t1 = bf2f(ta[1]), t2 = bf2f(ta[2]), t3 = bf2f(ta[3]);

  int j0 = sidx[(size_t)i * 3 + 0];
  int j1 = sidx[(size_t)i * 3 + 1];
  int j2 = sidx[(size_t)i * 3 + 2];
  bool v0 = (j0 >= 0) & (j0 < BDIM) & (j0 != i);
  bool v1 = (j1 >= 0) & (j1 < BDIM) & (j1 != i) & !(v0 & (j1 == j0));
  bool v2 = (j2 >= 0) & (j2 < BDIM) & (j2 != i) & !(v0 & (j2 == j0)) &
            !(v1 & (j2 == j1));

  float corr = 0.0f;
  {  // diagonal: replace 0.7*max(s,0)^2 with (s-1)^2
    u16x4 va = reinterpret_cast<const u16x4*>(vn + (size_t)i * DDIM)[lane];
    float d = t0 * bf2f(va[0]) + t1 * bf2f(va[1]) + t2 * bf2f(va[2]) +
              t3 * bf2f(va[3]);
    #pragma unroll
    for (int off = 1; off < 64; off <<= 1) d += __shfl_xor(d, off, 64);
    float u = fmaxf(d, 0.0f);
    corr += (d - 1.0f) * (d - 1.0f) - 0.7f * u * u;
  }
  int jj[3] = {j0, j1, j2};
  bool vv[3] = {v0, v1, v2};
  #pragma unroll
  for (int k = 0; k < 3; ++k) {
    int j = vv[k] ? jj[k] : i;  // safe address; discarded if invalid
    u16x4 va = reinterpret_cast<const u16x4*>(vn + (size_t)j * DDIM)[lane];
    float d = t0 * bf2f(va[0]) + t1 * bf2f(va[1]) + t2 * bf2f(va[2]) +
              t3 * bf2f(va[3]);
    #pragma unroll
    for (int off = 1; off < 64; off <<= 1) d += __shfl_xor(d, off, 64);
    if (vv[k]) {
      float up = fmaxf(0.7f - d, 0.0f);
      float un = fmaxf(d, 0.0f);
      corr += 0.7f * (up * up - un * un);  // GAMMA_SEMI == LAMBDA_NEG == 0.7
    }
  }
  if (lane == 0) atomicAdd(&slots[i & (NSLOTS - 1)], corr);
}

// ---------------------------------------------------------------------------
// Kernel 4: sum the 512 slots -> out (plain store, no memset of out needed).
// ---------------------------------------------------------------------------
__global__ __launch_bounds__(256) void reduce_kernel(
    const float* __restrict__ slots, float* __restrict__ out) {
  __shared__ float rb[4];
  int tid = threadIdx.x;
  float s = slots[tid] + slots[tid + 256];
  #pragma unroll
  for (int off = 1; off < 64; off <<= 1) s += __shfl_xor(s, off, 64);
  if ((tid & 63) == 0) rb[tid >> 6] = s;
  __syncthreads();
  if (tid == 0) out[0] = rb[0] + rb[1] + rb[2] + rb[3];
}

extern "C" void kernel_launch(void* const* d_in, const int* in_sizes, int n_in,
                              void* d_out, int out_size, void* d_ws,
                              size_t ws_size, hipStream_t stream) {
  const float* t = (const float*)d_in[0];
  const float* v = (const float*)d_in[1];
  const int* sidx = (const int*)d_in[2];
  float* out = (float*)d_out;
  float* slots = (float*)d_ws;  // 512 floats (4 KB reserved)
  unsigned short* tn = (unsigned short*)((char*)d_ws + 4096);  // 4 MB
  unsigned short* vn = tn + (size_t)BDIM * DDIM;               // 4 MB

  hipMemsetAsync(slots, 0, NSLOTS * sizeof(float), stream);
  norm_convert_kernel<<<4096, 256, 0, stream>>>(t, v, tn, vn);
  dim3 grid(64, 64);
  loss_kernel<<<grid, 256, 0, stream>>>(tn, vn, slots);
  corr_kernel<<<2048, 256, 0, stream>>>(tn, vn, sidx, slots);
  reduce_kernel<<<1, 256, 0, stream>>>(slots, out);
}